// Round 2
// baseline (84.958 us; speedup 1.0000x reference)
//
#include <hip/hip_runtime.h>

namespace {
constexpr int C = 128;
constexpr int P = 32;
constexpr int M = 2;
constexpr int HW = 256 * 256;
constexpr int B = 8;
constexpr int PPT = 2;                          // adjacent pixels per thread
constexpr int BLOCK = 256;
constexpr int PIX_PER_BLK = BLOCK * PPT;        // 512
constexpr int BLKS_PER_IMG = HW / PIX_PER_BLK;  // 128

// ws layout (floats): [P] w2half | [P] alphap | [P] g2 | [P] U0 | [P] U1 | [C*P] Wt (Wt[c][p])
__global__ void prep_kernel(const float* __restrict__ Wp,
                            const float* __restrict__ beta,
                            const float* __restrict__ alpha,
                            const float* __restrict__ gam,
                            float* __restrict__ ws) {
  const int t = threadIdx.x;
  if (t < P) {
    const int p = t;
    float w2 = 0.f;
    for (int c = 0; c < C; ++c) {
      const float w = Wp[p * C + c];
      w2 = fmaf(w, w, w2);
    }
    ws[p] = 0.5f * w2;
    ws[P + p] = 0.99f / (1.f + __expf(-alpha[p]));
    const float g = gam[p];
    ws[2 * P + p] = g * g;
    const float b0 = beta[p * M + 0], b1 = beta[p * M + 1];
    const float q0 = b0 * b0, q1 = b1 * b1;
    const float inv = 1.f / (q0 + q1);
    ws[3 * P + p] = q0 * inv;
    ws[4 * P + p] = q1 * inv;
  }
  float* Wt = ws + 5 * P;
  for (int i = t; i < C * P; i += BLOCK) {
    const int c = i >> 5, p = i & 31;
    Wt[i] = Wp[p * C + c];
  }
}

__global__ __launch_bounds__(BLOCK) void evid_kernel(
    const float* __restrict__ x, const float* __restrict__ ws,
    float* __restrict__ out) {
  const float* __restrict__ Wt = ws + 5 * P;
  const int blk = blockIdx.x;
  const int b = blk / BLKS_PER_IMG;
  const int s0 = (blk % BLKS_PER_IMG) * PIX_PER_BLK + threadIdx.x * PPT;
  const float* __restrict__ xb = x + (size_t)b * C * HW + s0;

  float dot[P][PPT];
#pragma unroll
  for (int p = 0; p < P; ++p)
#pragma unroll
    for (int k = 0; k < PPT; ++k) dot[p][k] = 0.f;
  float x2[PPT] = {0.f, 0.f};

#pragma unroll 8
  for (int c = 0; c < C; ++c) {
    const float2 xv = *reinterpret_cast<const float2*>(xb + (size_t)c * HW);
    const float xa[PPT] = {xv.x, xv.y};
#pragma unroll
    for (int k = 0; k < PPT; ++k) x2[k] = fmaf(xa[k], xa[k], x2[k]);
#pragma unroll
    for (int p = 0; p < P; ++p) {
      const float wv = Wt[c * P + p];  // wave-uniform -> scalar load
#pragma unroll
      for (int k = 0; k < PPT; ++k) dot[p][k] = fmaf(xa[k], wv, dot[p][k]);
    }
  }

  float cls0[PPT], cls1[PPT], om[PPT];
#pragma unroll
  for (int k = 0; k < PPT; ++k) {
    cls0[k] = 0.f;
    cls1[k] = 0.f;
    om[k] = 1.f;
  }

#pragma unroll
  for (int p = 0; p < P; ++p) {
    const float w2h = ws[p];
    const float ap = ws[P + p];
    const float g2 = ws[2 * P + p];
    const float U0 = ws[3 * P + p];
    const float U1 = ws[4 * P + p];
#pragma unroll
    for (int k = 0; k < PPT; ++k) {
      const float d = fmaf(0.5f, x2[k], w2h) - dot[p][k];
      const float s = ap * __expf(-g2 * d);
      const float mO = 1.f - s;
      const float mj0 = U0 * s, mj1 = U1 * s;
      cls0[k] = cls0[k] * (mj0 + mO) + mj0 * om[k];
      cls1[k] = cls1[k] * (mj1 + mO) + mj1 * om[k];
      om[k] *= mO;
    }
  }

  float o0[PPT], o1[PPT], o2[PPT];
#pragma unroll
  for (int k = 0; k < PPT; ++k) {
    const float tot = cls0[k] + cls1[k] + om[k];
    const float inv = 1.f / tot;
    o0[k] = cls0[k] * inv;
    o1[k] = cls1[k] * inv;
    o2[k] = om[k] * inv;
  }
  float* ob = out + (size_t)b * 3 * HW + s0;
  *reinterpret_cast<float2*>(ob) = make_float2(o0[0], o0[1]);
  *reinterpret_cast<float2*>(ob + HW) = make_float2(o1[0], o1[1]);
  *reinterpret_cast<float2*>(ob + 2 * HW) = make_float2(o2[0], o2[1]);
}
}  // namespace

extern "C" void kernel_launch(void* const* d_in, const int* in_sizes, int n_in,
                              void* d_out, int out_size, void* d_ws, size_t ws_size,
                              hipStream_t stream) {
  const float* feats = (const float*)d_in[0];
  const float* Wp = (const float*)d_in[1];
  const float* beta = (const float*)d_in[2];
  const float* alpha = (const float*)d_in[3];
  const float* gam = (const float*)d_in[4];
  float* ws = (float*)d_ws;
  float* out = (float*)d_out;

  hipLaunchKernelGGL(prep_kernel, dim3(1), dim3(BLOCK), 0, stream, Wp, beta,
                     alpha, gam, ws);
  hipLaunchKernelGGL(evid_kernel, dim3(B * BLKS_PER_IMG), dim3(BLOCK), 0,
                     stream, feats, ws, out);
}

// Round 3
// 72.705 us; speedup vs baseline: 1.1685x; 1.1685x over previous
//
#include <hip/hip_runtime.h>

namespace {
constexpr int C = 128;
constexpr int P = 32;
constexpr int HW = 256 * 256;
constexpr int B = 8;
constexpr int TPX = 64;                  // pixels per block tile
constexpr int BLOCK = 256;
constexpr int BLKS_PER_IMG = HW / TPX;   // 1024
constexpr int XROW = 264;                // LDS bytes per px row: 128 bf16 + 4B pad (8B-aligned)

typedef __attribute__((ext_vector_type(8))) short short8;
typedef __attribute__((ext_vector_type(4))) float f32x4;

__device__ inline unsigned short f2bf(float f) {
  unsigned u = __builtin_bit_cast(unsigned, f);
  return (unsigned short)((u + 0x7FFFu + ((u >> 16) & 1u)) >> 16);  // RNE
}

// ws floats: [0:32) 0.5*|W_p|^2 | [32:64) alphap | [64:96) g2 | [96:128) U0 | [128:160) U1
// then ushort W_bf16[32*128] at (ws+160), row-major [p][c]
__global__ void prep_kernel(const float* __restrict__ Wp,
                            const float* __restrict__ beta,
                            const float* __restrict__ alpha,
                            const float* __restrict__ gam,
                            float* __restrict__ ws) {
  const int t = threadIdx.x;
  if (t < P) {
    const int p = t;
    float w2 = 0.f;
    for (int c = 0; c < C; ++c) {
      const float w = Wp[p * C + c];
      w2 = fmaf(w, w, w2);
    }
    ws[p] = 0.5f * w2;
    ws[32 + p] = 0.99f / (1.f + __expf(-alpha[p]));
    const float g = gam[p];
    ws[64 + p] = g * g;
    const float b0 = beta[p * 2 + 0], b1 = beta[p * 2 + 1];
    const float q0 = b0 * b0, q1 = b1 * b1;
    const float inv = 1.f / (q0 + q1);
    ws[96 + p] = q0 * inv;
    ws[128 + p] = q1 * inv;
  }
  unsigned short* wbf = (unsigned short*)(ws + 160);
  for (int i = t; i < P * C; i += BLOCK) wbf[i] = f2bf(Wp[i]);
}

__global__ __launch_bounds__(BLOCK) void evid_kernel(const float* __restrict__ x,
                                                     const float* __restrict__ ws,
                                                     float* __restrict__ out) {
  __shared__ __align__(16) unsigned char xlds[TPX * XROW];  // 16.9 KB bf16 [px][c]
  __shared__ __align__(16) float part[TPX][12];             // x^2 partials [px][cg]

  const int t = threadIdx.x;
  const int blk = blockIdx.x;
  const int b = blk >> 10;                // image
  const int px0 = (blk & (BLKS_PER_IMG - 1)) << 6;
  const float* __restrict__ xg = x + (size_t)b * C * HW + px0;

  // ---- stage: f32 global -> bf16 LDS (transpose to [px][c]) + x^2 partials ----
  {
    const int pxl = (t & 31) * 2;
    const int cg = t >> 5;                // 0..7, covers 16 channels each
    float sx0 = 0.f, sx1 = 0.f;
    unsigned char* row0 = xlds + pxl * XROW;
    unsigned char* row1 = row0 + XROW;
#pragma unroll
    for (int i = 0; i < 8; ++i) {
      const int c = cg * 16 + 2 * i;
      const float2 a = *reinterpret_cast<const float2*>(xg + (size_t)c * HW + pxl);
      const float2 d = *reinterpret_cast<const float2*>(xg + (size_t)(c + 1) * HW + pxl);
      sx0 = fmaf(a.x, a.x, fmaf(d.x, d.x, sx0));
      sx1 = fmaf(a.y, a.y, fmaf(d.y, d.y, sx1));
      *reinterpret_cast<unsigned*>(row0 + c * 2) =
          (unsigned)f2bf(a.x) | ((unsigned)f2bf(d.x) << 16);
      *reinterpret_cast<unsigned*>(row1 + c * 2) =
          (unsigned)f2bf(a.y) | ((unsigned)f2bf(d.y) << 16);
    }
    part[pxl][cg] = sx0;
    part[pxl + 1][cg] = sx1;
  }
  __syncthreads();

  // ---- compute: per wave, 16 px; A=W[16p x 32c] (regs), B=x[32c x 16px] (LDS) ----
  const int w = t >> 6;
  const int l = t & 63;
  const int li = l & 15;                  // pixel column / A row
  const int g = l >> 4;                   // k-group
  const int pxw = w * 16 + li;            // local pixel this lane owns (C col)

  // B fragments: 4 k-steps, lane reads x_bf16[pxw][k0 + g*8 .. +7]
  short8 bfr[4];
  {
    const unsigned char* xr = xlds + pxw * XROW + 16 * g;
#pragma unroll
    for (int s = 0; s < 4; ++s) {
      const uint2 lo = *reinterpret_cast<const uint2*>(xr + 64 * s);
      const uint2 hi = *reinterpret_cast<const uint2*>(xr + 64 * s + 8);
      union { unsigned u[4]; short8 v; } uu;
      uu.u[0] = lo.x; uu.u[1] = lo.y; uu.u[2] = hi.x; uu.u[3] = hi.y;
      bfr[s] = uu.v;
    }
  }
  // A fragments: lane reads W_bf16[T*16+li][k0 + g*8 .. +7]
  const unsigned short* __restrict__ wbf = (const unsigned short*)(ws + 160);
  short8 afr[2][4];
#pragma unroll
  for (int T = 0; T < 2; ++T)
#pragma unroll
    for (int s = 0; s < 4; ++s) {
      const uint4 q = *reinterpret_cast<const uint4*>(wbf + (T * 16 + li) * C + s * 32 + g * 8);
      union { uint4 q; short8 v; } uu;
      uu.q = q;
      afr[T][s] = uu.v;
    }

  f32x4 acc0 = {0.f, 0.f, 0.f, 0.f};
  f32x4 acc1 = {0.f, 0.f, 0.f, 0.f};
#pragma unroll
  for (int s = 0; s < 4; ++s) {
    acc0 = __builtin_amdgcn_mfma_f32_16x16x32_bf16(afr[0][s], bfr[s], acc0, 0, 0, 0);
    acc1 = __builtin_amdgcn_mfma_f32_16x16x32_bf16(afr[1][s], bfr[s], acc1, 0, 0, 0);
  }

  // x2 for this lane's pixel
  const f32x4 q0 = *reinterpret_cast<const f32x4*>(&part[pxw][0]);
  const f32x4 q1 = *reinterpret_cast<const f32x4*>(&part[pxw][4]);
  const float x2v = 0.5f * ((q0.x + q0.y + q0.z + q0.w) + (q1.x + q1.y + q1.z + q1.w));

  // lane-local DS combine over this lane's 8 prototypes (rows g*4+r, tiles 0/1)
  float c0 = 0.f, c1 = 0.f, om = 1.f;
#pragma unroll
  for (int r = 0; r < 4; ++r) {
#pragma unroll
    for (int T = 0; T < 2; ++T) {
      const int p = T * 16 + g * 4 + r;
      const float dotv = (T == 0) ? acc0[r] : acc1[r];
      const float dd = x2v + ws[p] - dotv;                 // 0.5||x-w||^2
      const float sv = ws[32 + p] * __expf(-ws[64 + p] * dd);
      const float mO = 1.f - sv;
      const float m0 = ws[96 + p] * sv, m1 = ws[128 + p] * sv;
      const float n0 = fmaf(c0, m0 + mO, m0 * om);
      const float n1 = fmaf(c1, m1 + mO, m1 * om);
      om *= mO;
      c0 = n0;
      c1 = n1;
    }
  }
  // merge across the 4 lanes (g groups) sharing this pixel: Dempster merge is associative
#pragma unroll
  for (int mask = 16; mask <= 32; mask <<= 1) {
    const float b0 = __shfl_xor(c0, mask);
    const float b1 = __shfl_xor(c1, mask);
    const float bO = __shfl_xor(om, mask);
    const float n0 = c0 * b0 + c0 * bO + om * b0;
    const float n1 = c1 * b1 + c1 * bO + om * b1;
    om *= bO;
    c0 = n0;
    c1 = n1;
  }

  if (g == 0) {
    const float inv = 1.f / (c0 + c1 + om);
    float* ob = out + (size_t)b * 3 * HW + px0 + w * 16 + li;
    ob[0] = c0 * inv;
    ob[HW] = c1 * inv;
    ob[2 * HW] = om * inv;
  }
}
}  // namespace

extern "C" void kernel_launch(void* const* d_in, const int* in_sizes, int n_in,
                              void* d_out, int out_size, void* d_ws, size_t ws_size,
                              hipStream_t stream) {
  const float* feats = (const float*)d_in[0];
  const float* Wp = (const float*)d_in[1];
  const float* beta = (const float*)d_in[2];
  const float* alpha = (const float*)d_in[3];
  const float* gam = (const float*)d_in[4];
  float* ws = (float*)d_ws;
  float* out = (float*)d_out;

  hipLaunchKernelGGL(prep_kernel, dim3(1), dim3(BLOCK), 0, stream, Wp, beta,
                     alpha, gam, ws);
  hipLaunchKernelGGL(evid_kernel, dim3(B * BLKS_PER_IMG), dim3(BLOCK), 0,
                     stream, feats, ws, out);
}

// Round 4
// 57.361 us; speedup vs baseline: 1.4811x; 1.2675x over previous
//
#include <hip/hip_runtime.h>

namespace {
constexpr int C = 128;
constexpr int P = 32;
constexpr int HW = 256 * 256;
constexpr int B = 8;
constexpr int PXW = 32;                        // pixels per wave (2 col-tiles of 16)
constexpr int BLOCK = 256;                     // 4 waves
constexpr int PIX_PER_BLK = 4 * PXW;           // 128
constexpr int BLKS_PER_IMG = HW / PIX_PER_BLK; // 512

typedef __attribute__((ext_vector_type(8))) short short8;
typedef __attribute__((ext_vector_type(4))) float f32x4;

__device__ inline unsigned short f2bf(float f) {
  unsigned u = __builtin_bit_cast(unsigned, f);
  return (unsigned short)((u + 0x7FFFu + ((u >> 16) & 1u)) >> 16);  // RNE
}
__device__ inline unsigned pack2(float lo, float hi) {
  return (unsigned)f2bf(lo) | ((unsigned)f2bf(hi) << 16);
}

// ws floats: [0:32) 0.5*|W_p|^2 | [32:64) alphap | [64:96) g2 | [96:128) U0 | [128:160) U1
// then ushort W_bf16[32*128] at (ws+160), row-major [p][c]
__global__ void prep_kernel(const float* __restrict__ Wp,
                            const float* __restrict__ beta,
                            const float* __restrict__ alpha,
                            const float* __restrict__ gam,
                            float* __restrict__ ws) {
  const int t = threadIdx.x;
  {
    const int p = t >> 3, seg = t & 7;  // 8 threads per prototype
    float s = 0.f;
#pragma unroll
    for (int i = 0; i < 16; ++i) {
      const float w = Wp[p * C + seg * 16 + i];
      s = fmaf(w, w, s);
    }
#pragma unroll
    for (int m = 1; m < 8; m <<= 1) s += __shfl_xor(s, m);
    if (seg == 0) {
      ws[p] = 0.5f * s;
      ws[32 + p] = 0.99f / (1.f + __expf(-alpha[p]));
      const float gv = gam[p];
      ws[64 + p] = gv * gv;
      const float b0 = beta[p * 2 + 0], b1 = beta[p * 2 + 1];
      const float q0 = b0 * b0, q1 = b1 * b1;
      const float inv = 1.f / (q0 + q1);
      ws[96 + p] = q0 * inv;
      ws[128 + p] = q1 * inv;
    }
  }
  unsigned short* wbf = (unsigned short*)(ws + 160);
  for (int i = t; i < P * C; i += BLOCK) wbf[i] = f2bf(Wp[i]);
}

__global__ __launch_bounds__(BLOCK) void evid_kernel(const float* __restrict__ x,
                                                     const float* __restrict__ ws,
                                                     float* __restrict__ out) {
  const int t = threadIdx.x;
  const int blk = blockIdx.x;
  const int b = blk >> 9;  // blk / BLKS_PER_IMG
  const int px_blk = (blk & (BLKS_PER_IMG - 1)) * PIX_PER_BLK;
  const int wid = t >> 6, l = t & 63;
  const int li = l & 15;   // column within 16-px tile
  const int g = l >> 4;    // k-group (0..3)
  const int px_wave = px_blk + wid * PXW;
  // lane's base: x[b, c, px_wave + li], col-tile 1 is +16
  const float* __restrict__ xg = x + (size_t)b * C * HW + px_wave + li;
  const unsigned short* __restrict__ wbf = (const unsigned short*)(ws + 160);

  f32x4 acc00 = {0.f, 0.f, 0.f, 0.f};  // [cg0][T0]
  f32x4 acc01 = {0.f, 0.f, 0.f, 0.f};  // [cg0][T1]
  f32x4 acc10 = {0.f, 0.f, 0.f, 0.f};  // [cg1][T0]
  f32x4 acc11 = {0.f, 0.f, 0.f, 0.f};  // [cg1][T1]
  float xs0 = 0.f, xs1 = 0.f;          // x^2 partials per col-tile
  const int krow0 = g * 8;

#pragma unroll
  for (int s = 0; s < 4; ++s) {
    const float* xr = xg + (size_t)(s * 32 + krow0) * HW;
    float bx0[8], bx1[8];
#pragma unroll
    for (int j = 0; j < 8; ++j) {
      bx0[j] = xr[(size_t)j * HW];       // col-tile 0
      bx1[j] = xr[(size_t)j * HW + 16];  // col-tile 1
    }
    union { uint4 q; short8 v; } a0, a1;
    a0.q = *reinterpret_cast<const uint4*>(wbf + (0 * 16 + li) * C + s * 32 + krow0);
    a1.q = *reinterpret_cast<const uint4*>(wbf + (16 + li) * C + s * 32 + krow0);
    union { unsigned u[4]; short8 v; } b0, b1;
#pragma unroll
    for (int j = 0; j < 4; ++j) {
      b0.u[j] = pack2(bx0[2 * j], bx0[2 * j + 1]);
      b1.u[j] = pack2(bx1[2 * j], bx1[2 * j + 1]);
    }
#pragma unroll
    for (int j = 0; j < 8; ++j) {
      xs0 = fmaf(bx0[j], bx0[j], xs0);
      xs1 = fmaf(bx1[j], bx1[j], xs1);
    }
    acc00 = __builtin_amdgcn_mfma_f32_16x16x32_bf16(a0.v, b0.v, acc00, 0, 0, 0);
    acc01 = __builtin_amdgcn_mfma_f32_16x16x32_bf16(a1.v, b0.v, acc01, 0, 0, 0);
    acc10 = __builtin_amdgcn_mfma_f32_16x16x32_bf16(a0.v, b1.v, acc10, 0, 0, 0);
    acc11 = __builtin_amdgcn_mfma_f32_16x16x32_bf16(a1.v, b1.v, acc11, 0, 0, 0);
  }

  // full x^2 per pixel: reduce partials over the 4 k-group lanes
#pragma unroll
  for (int mask = 16; mask <= 32; mask <<= 1) {
    xs0 += __shfl_xor(xs0, mask);
    xs1 += __shfl_xor(xs1, mask);
  }
  const float x2v0 = 0.5f * xs0;
  const float x2v1 = 0.5f * xs1;

  // lane-local Dempster combine over this lane's 8 prototypes, both col-tiles
  float c00 = 0.f, c01 = 0.f, om0 = 1.f;  // col-tile 0: class0, class1, omega
  float c10 = 0.f, c11 = 0.f, om1 = 1.f;  // col-tile 1
#pragma unroll
  for (int r = 0; r < 4; ++r) {
#pragma unroll
    for (int T = 0; T < 2; ++T) {
      const int p = T * 16 + g * 4 + r;
      const float w2h = ws[p];
      const float ap = ws[32 + p];
      const float g2 = ws[64 + p];
      const float U0 = ws[96 + p];
      const float U1 = ws[128 + p];
      const float dot0 = (T == 0) ? acc00[r] : acc01[r];
      const float dot1 = (T == 0) ? acc10[r] : acc11[r];
      {
        const float d = x2v0 + w2h - dot0;
        const float sv = ap * __expf(-g2 * d);
        const float mO = 1.f - sv;
        const float m0 = U0 * sv, m1 = U1 * sv;
        const float n0 = fmaf(c00, m0 + mO, m0 * om0);
        const float n1 = fmaf(c01, m1 + mO, m1 * om0);
        om0 *= mO;
        c00 = n0; c01 = n1;
      }
      {
        const float d = x2v1 + w2h - dot1;
        const float sv = ap * __expf(-g2 * d);
        const float mO = 1.f - sv;
        const float m0 = U0 * sv, m1 = U1 * sv;
        const float n0 = fmaf(c10, m0 + mO, m0 * om1);
        const float n1 = fmaf(c11, m1 + mO, m1 * om1);
        om1 *= mO;
        c10 = n0; c11 = n1;
      }
    }
  }
  // merge across the 4 k-group lanes (Dempster combine is associative+commutative)
#pragma unroll
  for (int mask = 16; mask <= 32; mask <<= 1) {
    {
      const float b0 = __shfl_xor(c00, mask);
      const float b1 = __shfl_xor(c01, mask);
      const float bO = __shfl_xor(om0, mask);
      const float n0 = c00 * b0 + c00 * bO + om0 * b0;
      const float n1 = c01 * b1 + c01 * bO + om0 * b1;
      om0 *= bO; c00 = n0; c01 = n1;
    }
    {
      const float b0 = __shfl_xor(c10, mask);
      const float b1 = __shfl_xor(c11, mask);
      const float bO = __shfl_xor(om1, mask);
      const float n0 = c10 * b0 + c10 * bO + om1 * b0;
      const float n1 = c11 * b1 + c11 * bO + om1 * b1;
      om1 *= bO; c10 = n0; c11 = n1;
    }
  }

  if (g < 2) {  // g==0 stores col-tile 0, g==1 stores col-tile 1 -> 128 B contiguous
    const float a = (g == 0) ? c00 : c10;
    const float bb = (g == 0) ? c01 : c11;
    const float oo = (g == 0) ? om0 : om1;
    const float inv = 1.f / (a + bb + oo);
    float* ob = out + (size_t)b * 3 * HW + px_wave + g * 16 + li;
    ob[0] = a * inv;
    ob[HW] = bb * inv;
    ob[2 * HW] = oo * inv;
  }
}
}  // namespace

extern "C" void kernel_launch(void* const* d_in, const int* in_sizes, int n_in,
                              void* d_out, int out_size, void* d_ws, size_t ws_size,
                              hipStream_t stream) {
  const float* feats = (const float*)d_in[0];
  const float* Wp = (const float*)d_in[1];
  const float* beta = (const float*)d_in[2];
  const float* alpha = (const float*)d_in[3];
  const float* gam = (const float*)d_in[4];
  float* ws = (float*)d_ws;
  float* out = (float*)d_out;

  hipLaunchKernelGGL(prep_kernel, dim3(1), dim3(BLOCK), 0, stream, Wp, beta,
                     alpha, gam, ws);
  hipLaunchKernelGGL(evid_kernel, dim3(B * BLKS_PER_IMG), dim3(BLOCK), 0,
                     stream, feats, ws, out);
}

// Round 5
// 51.255 us; speedup vs baseline: 1.6576x; 1.1191x over previous
//
#include <hip/hip_runtime.h>

namespace {
constexpr int C = 128;
constexpr int P = 32;
constexpr int HW = 256 * 256;
constexpr int B = 8;
constexpr int PXW = 32;                        // pixels per wave (2 col-tiles: even/odd)
constexpr int BLOCK = 256;                     // 4 waves
constexpr int PIX_PER_BLK = 4 * PXW;           // 128
constexpr int BLKS_PER_IMG = HW / PIX_PER_BLK; // 512
constexpr int PREP_BLKS = 8;

typedef __attribute__((ext_vector_type(8))) short short8;
typedef __attribute__((ext_vector_type(4))) float f32x4;

__device__ inline unsigned short f2bf(float f) {
  unsigned u = __builtin_bit_cast(unsigned, f);
  return (unsigned short)((u + 0x7FFFu + ((u >> 16) & 1u)) >> 16);  // RNE
}
// one-instr packed f32->bf16 (RNE), T12 pattern
__device__ inline unsigned pack2(float lo, float hi) {
  unsigned r;
  asm("v_cvt_pk_bf16_f32 %0, %1, %2" : "=v"(r) : "v"(lo), "v"(hi));
  return r;
}

// ws floats: [0:32) 0.5*|W_p|^2 | [32:64) alphap | [64:96) g2 | [96:128) U0 | [128:160) U1
// then ushort W_bf16[32*128] at (ws+160), row-major [p][c]
__global__ void prep_kernel(const float* __restrict__ Wp,
                            const float* __restrict__ beta,
                            const float* __restrict__ alpha,
                            const float* __restrict__ gam,
                            float* __restrict__ ws) {
  const int t = threadIdx.x;
  if (blockIdx.x == 0) {
    const int p = t >> 3, seg = t & 7;  // 8 threads per prototype
    float s = 0.f;
#pragma unroll
    for (int i = 0; i < 16; ++i) {
      const float w = Wp[p * C + seg * 16 + i];
      s = fmaf(w, w, s);
    }
#pragma unroll
    for (int m = 1; m < 8; m <<= 1) s += __shfl_xor(s, m);
    if (seg == 0) {
      ws[p] = 0.5f * s;
      ws[32 + p] = 0.99f / (1.f + __expf(-alpha[p]));
      const float gv = gam[p];
      ws[64 + p] = gv * gv;
      const float b0 = beta[p * 2 + 0], b1 = beta[p * 2 + 1];
      const float q0 = b0 * b0, q1 = b1 * b1;
      const float inv = 1.f / (q0 + q1);
      ws[96 + p] = q0 * inv;
      ws[128 + p] = q1 * inv;
    }
  }
  unsigned short* wbf = (unsigned short*)(ws + 160);
  for (int i = blockIdx.x * BLOCK + t; i < P * C; i += PREP_BLKS * BLOCK)
    wbf[i] = f2bf(Wp[i]);
}

__global__ __launch_bounds__(BLOCK) void evid_kernel(const float* __restrict__ x,
                                                     const float* __restrict__ ws,
                                                     float* __restrict__ out) {
  const int t = threadIdx.x;
  const int blk = blockIdx.x;
  const int b = blk >> 9;  // blk / BLKS_PER_IMG
  const int px_blk = (blk & (BLKS_PER_IMG - 1)) * PIX_PER_BLK;
  const int wid = t >> 6, l = t & 63;
  const int li = l & 15;   // column within 16-px tile
  const int g = l >> 4;    // k-group (0..3)
  const int px_wave = px_blk + wid * PXW;
  // lane owns pixels px_wave + 2*li (even/tile0) and +1 (odd/tile1)
  const float* __restrict__ xg = x + (size_t)b * C * HW + px_wave + 2 * li;
  const unsigned short* __restrict__ wbf = (const unsigned short*)(ws + 160);

  f32x4 acc00 = {0.f, 0.f, 0.f, 0.f};  // even, proto-tile0
  f32x4 acc01 = {0.f, 0.f, 0.f, 0.f};  // even, proto-tile1
  f32x4 acc10 = {0.f, 0.f, 0.f, 0.f};  // odd,  proto-tile0
  f32x4 acc11 = {0.f, 0.f, 0.f, 0.f};  // odd,  proto-tile1
  float xs0 = 0.f, xs1 = 0.f;          // x^2 partials (even/odd)
  const int krow0 = g * 8;

#pragma unroll
  for (int s = 0; s < 4; ++s) {
    const float* xr = xg + (size_t)(s * 32 + krow0) * HW;
    float2 v[8];
#pragma unroll
    for (int j = 0; j < 8; ++j)
      v[j] = *reinterpret_cast<const float2*>(xr + (size_t)j * HW);
    union { uint4 q; short8 s8; } a0, a1;
    a0.q = *reinterpret_cast<const uint4*>(wbf + li * C + s * 32 + krow0);
    a1.q = *reinterpret_cast<const uint4*>(wbf + (16 + li) * C + s * 32 + krow0);
    union { unsigned u[4]; short8 s8; } b0, b1;
#pragma unroll
    for (int j = 0; j < 4; ++j) {
      b0.u[j] = pack2(v[2 * j].x, v[2 * j + 1].x);
      b1.u[j] = pack2(v[2 * j].y, v[2 * j + 1].y);
    }
#pragma unroll
    for (int j = 0; j < 8; ++j) {
      xs0 = fmaf(v[j].x, v[j].x, xs0);
      xs1 = fmaf(v[j].y, v[j].y, xs1);
    }
    acc00 = __builtin_amdgcn_mfma_f32_16x16x32_bf16(a0.s8, b0.s8, acc00, 0, 0, 0);
    acc01 = __builtin_amdgcn_mfma_f32_16x16x32_bf16(a1.s8, b0.s8, acc01, 0, 0, 0);
    acc10 = __builtin_amdgcn_mfma_f32_16x16x32_bf16(a0.s8, b1.s8, acc10, 0, 0, 0);
    acc11 = __builtin_amdgcn_mfma_f32_16x16x32_bf16(a1.s8, b1.s8, acc11, 0, 0, 0);
  }

  // full x^2 per pixel: reduce partials over the 4 k-group lanes
#pragma unroll
  for (int mask = 16; mask <= 32; mask <<= 1) {
    xs0 += __shfl_xor(xs0, mask);
    xs1 += __shfl_xor(xs1, mask);
  }
  const float x2v0 = 0.5f * xs0;
  const float x2v1 = 0.5f * xs1;

  // lane-local Dempster combine over this lane's 8 prototypes, both pixels
  float c00 = 0.f, c01 = 0.f, om0 = 1.f;  // even px
  float c10 = 0.f, c11 = 0.f, om1 = 1.f;  // odd px
#pragma unroll
  for (int r = 0; r < 4; ++r) {
#pragma unroll
    for (int T = 0; T < 2; ++T) {
      const int p = T * 16 + g * 4 + r;
      const float w2h = ws[p];
      const float ap = ws[32 + p];
      const float g2 = ws[64 + p];
      const float U0 = ws[96 + p];
      const float U1 = ws[128 + p];
      const float dot0 = (T == 0) ? acc00[r] : acc01[r];
      const float dot1 = (T == 0) ? acc10[r] : acc11[r];
      {
        const float d = x2v0 + w2h - dot0;
        const float sv = ap * __expf(-g2 * d);
        const float mO = 1.f - sv;
        const float m0 = U0 * sv, m1 = U1 * sv;
        const float n0 = fmaf(c00, m0 + mO, m0 * om0);
        const float n1 = fmaf(c01, m1 + mO, m1 * om0);
        om0 *= mO;
        c00 = n0; c01 = n1;
      }
      {
        const float d = x2v1 + w2h - dot1;
        const float sv = ap * __expf(-g2 * d);
        const float mO = 1.f - sv;
        const float m0 = U0 * sv, m1 = U1 * sv;
        const float n0 = fmaf(c10, m0 + mO, m0 * om1);
        const float n1 = fmaf(c11, m1 + mO, m1 * om1);
        om1 *= mO;
        c10 = n0; c11 = n1;
      }
    }
  }
  // merge across the 4 k-group lanes (Dempster combine is associative+commutative)
#pragma unroll
  for (int mask = 16; mask <= 32; mask <<= 1) {
    {
      const float b0 = __shfl_xor(c00, mask);
      const float b1 = __shfl_xor(c01, mask);
      const float bO = __shfl_xor(om0, mask);
      const float n0 = c00 * b0 + c00 * bO + om0 * b0;
      const float n1 = c01 * b1 + c01 * bO + om0 * b1;
      om0 *= bO; c00 = n0; c01 = n1;
    }
    {
      const float b0 = __shfl_xor(c10, mask);
      const float b1 = __shfl_xor(c11, mask);
      const float bO = __shfl_xor(om1, mask);
      const float n0 = c10 * b0 + c10 * bO + om1 * b0;
      const float n1 = c11 * b1 + c11 * bO + om1 * b1;
      om1 *= bO; c10 = n0; c11 = n1;
    }
  }

  if (g == 0) {
    const float inve = __builtin_amdgcn_rcpf(c00 + c01 + om0);
    const float invo = __builtin_amdgcn_rcpf(c10 + c11 + om1);
    float* ob = out + (size_t)b * 3 * HW + px_wave + 2 * li;
    *reinterpret_cast<float2*>(ob) = make_float2(c00 * inve, c10 * invo);
    *reinterpret_cast<float2*>(ob + HW) = make_float2(c01 * inve, c11 * invo);
    *reinterpret_cast<float2*>(ob + 2 * HW) = make_float2(om0 * inve, om1 * invo);
  }
}
}  // namespace

extern "C" void kernel_launch(void* const* d_in, const int* in_sizes, int n_in,
                              void* d_out, int out_size, void* d_ws, size_t ws_size,
                              hipStream_t stream) {
  const float* feats = (const float*)d_in[0];
  const float* Wp = (const float*)d_in[1];
  const float* beta = (const float*)d_in[2];
  const float* alpha = (const float*)d_in[3];
  const float* gam = (const float*)d_in[4];
  float* ws = (float*)d_ws;
  float* out = (float*)d_out;

  hipLaunchKernelGGL(prep_kernel, dim3(PREP_BLKS), dim3(BLOCK), 0, stream, Wp,
                     beta, alpha, gam, ws);
  hipLaunchKernelGGL(evid_kernel, dim3(B * BLKS_PER_IMG), dim3(BLOCK), 0,
                     stream, feats, ws, out);
}